// Round 7
// baseline (26.078 us; speedup 1.0000x reference)
//
#include <hip/hip_runtime.h>

// BSEC_RNN: B=4096, T=2048, I=1, H=2, O=1.
//   h[t] = tanh(W_ih*x[t] + b_ih + b_hh + W_hh @ h[t-1]),  h[-1] = 0
//   out[t] = fc_w[0]*x[t] + fc_w[1]*h0[t] + fc_w[2]*h1[t] + fc_b
//
// Parallel-in-time (validated r2-r6, absmax 3.9e-3 = fp32 baseline): chunks
// of 32 steps, 32-step warm-up from h=0 (contraction ~0.5/step).
//
// WAVE-INDEPENDENT, ZERO-BARRIER: block = 1 wave = one (64-seq group, chunk)
// pair with 16 KB private LDS. Stage(coalesced f32x4 -> swizzled LDS) ->
// compute -> restage outputs -> coalesced NT store, all wave-local, so the
// ~10 resident waves/CU are phase-staggered and HBM/L3 never idles (r6's
// block-wide barriers serialized memory phases against compute).
//
// LDS layout (pair-swizzled, validated r6): group q = t/4 holds words
// [q*256 + 2*((seq^q)&63)] = (x_4q, x_4q+1), +128 = (x_4q+2, x_4q+3).
//
// Math (validated r6): state rr = (r0,r1), r = 1/(1+exp2(p)), h = 1-2r
// folded into coefficients; v_pk_fma_f32 op_sel broadcasts.

typedef float f32x2 __attribute__((ext_vector_type(2)));
typedef float f32x4 __attribute__((ext_vector_type(4)));

constexpr int T_LEN  = 2048;
constexpr int CHUNK  = 32;
constexpr int WARM   = 32;
constexpr int NCHUNK = T_LEN / CHUNK;   // 64 chunks/seq

static __device__ inline float EXP2F(float x){ float r; asm("v_exp_f32 %0, %1":"=v"(r):"v"(x)); return r; }
static __device__ inline float RCPF(float x){ float r; asm("v_rcp_f32 %0, %1":"=v"(r):"v"(x)); return r; }
static __device__ inline f32x2 mk2(float a, float b){ f32x2 t; t.x=a; t.y=b; return t; }

#define PK_FMA_B0(d, s0, s1, s2)                                          \
    asm("v_pk_fma_f32 %0, %1, %2, %3 op_sel:[0,0,0] op_sel_hi:[0,1,1]"    \
        : "=v"(d) : "v"(s0), "v"(s1), "v"(s2))
#define PK_FMA_B1(d, s0, s1, s2)                                          \
    asm("v_pk_fma_f32 %0, %1, %2, %3 op_sel:[1,0,0] op_sel_hi:[1,1,1]"    \
        : "=v"(d) : "v"(s0), "v"(s1), "v"(s2))
#define PK_ADD(d, s0, s1)                                                 \
    asm("v_pk_add_f32 %0, %1, %2" : "=v"(d) : "v"(s0), "v"(s1))

#define PSTEP_CORE(bb)                                                    \
    do {                                                                  \
        f32x2 q_, p_, e_, d_;                                             \
        PK_FMA_B1(q_, rr, mm1, (bb));                                     \
        PK_FMA_B0(p_, rr, mm0, q_);                                       \
        e_.x = EXP2F(p_.x); e_.y = EXP2F(p_.y);                           \
        PK_ADD(d_, e_, ones);                                             \
        rr.x = RCPF(d_.x); rr.y = RCPF(d_.y);                             \
    } while (0)

#define WSTEP_LO(xp2) do { f32x2 b_; PK_FMA_B0(b_, (xp2), aa, cc); PSTEP_CORE(b_); } while (0)
#define WSTEP_HI(xp2) do { f32x2 b_; PK_FMA_B1(b_, (xp2), aa, cc); PSTEP_CORE(b_); } while (0)
#define OSTEP_LO(xp2, ok) do { WSTEP_LO(xp2); (ok) = fmaf(rr.y, g2, fmaf(rr.x, g1, fmaf((xp2).x, f0, fb))); } while (0)
#define OSTEP_HI(xp2, ok) do { WSTEP_HI(xp2); (ok) = fmaf(rr.y, g2, fmaf(rr.x, g1, fmaf((xp2).y, f0, fb))); } while (0)

__global__ __launch_bounds__(64) void rnn_wave(
    const float* __restrict__ x,
    const float* __restrict__ W_ih,
    const float* __restrict__ W_hh,
    const float* __restrict__ b_ih,
    const float* __restrict__ b_hh,
    const float* __restrict__ fc_w,
    const float* __restrict__ fc_b,
    float* __restrict__ out)
{
    __shared__ float lx[4096];            // 16 KB, wave-private

    const int l   = threadIdx.x;          // lane = seq within 64-seq group
    const int wid = blockIdx.x;
    const int sg  = wid >> 6;             // sequence group
    const int c   = wid & (NCHUNK - 1);   // chunk index

    const int t0 = c ? c * CHUNK - WARM : 0;
    const int q0 = c ? (WARM >> 2) : 0;   // first chunk group (8 or 0)

    const float* xg = x + (size_t)(sg * 64) * T_LEN + t0;

    // ---- Stage: coalesced global f32x4 -> pair-swizzled LDS (wave-local) ----
    if (c) {
        // 16 f4-groups x 64 seqs
        #pragma unroll
        for (int k = 0; k < 16; ++k) {
            int s = (l >> 4) + (k << 2);
            int q = l & 15;
            f32x4 v = *(const f32x4*)(xg + (size_t)s * T_LEN + (q << 2));
            int A = q * 256 + (((s ^ q) & 63) << 1);
            *(f32x2*)&lx[A]       = mk2(v.x, v.y);
            *(f32x2*)&lx[A + 128] = mk2(v.z, v.w);
        }
    } else {
        // 8 f4-groups x 64 seqs
        #pragma unroll
        for (int k = 0; k < 8; ++k) {
            int s = (l >> 3) + (k << 3);
            int q = l & 7;
            f32x4 v = *(const f32x4*)(xg + (size_t)s * T_LEN + (q << 2));
            int A = q * 256 + (((s ^ q) & 63) << 1);
            *(f32x2*)&lx[A]       = mk2(v.x, v.y);
            *(f32x2*)&lx[A + 128] = mk2(v.z, v.w);
        }
    }
    // no __syncthreads(): all hazards are within this wave; the compiler
    // orders ds_write -> ds_read through lx.

    // ---- Coefficients (r-trick folding, s = 2*log2(e)) ----
    const float s2 = 2.0f * 1.44269504088896340736f;
    const float W00 = W_hh[0], W01 = W_hh[1], W10 = W_hh[2], W11 = W_hh[3];
    const f32x2 aa  = mk2(W_ih[0] * s2, W_ih[1] * s2);
    const f32x2 cc  = mk2((b_ih[0] + b_hh[0] + W00 + W01) * s2,
                          (b_ih[1] + b_hh[1] + W10 + W11) * s2);
    const f32x2 mm0 = mk2(-2.0f * s2 * W00, -2.0f * s2 * W10);
    const f32x2 mm1 = mk2(-2.0f * s2 * W01, -2.0f * s2 * W11);
    const f32x2 ones = mk2(1.0f, 1.0f);
    const float f0 = fc_w[0];
    const float g1 = -2.0f * fc_w[1], g2 = -2.0f * fc_w[2];
    const float fb = fc_b[0] + fc_w[1] + fc_w[2];

    f32x2 rr = mk2(0.5f, 0.5f);  // h = 0

    // ---- Warm-up: groups 0..7 (only when c > 0) ----
    if (c) {
        #pragma unroll
        for (int q = 0; q < 8; ++q) {
            int A = q * 256 + (((l ^ q) & 63) << 1);
            f32x2 xa = *(const f32x2*)&lx[A];
            f32x2 xb = *(const f32x2*)&lx[A + 128];
            WSTEP_LO(xa); WSTEP_HI(xa); WSTEP_LO(xb); WSTEP_HI(xb);
        }
    }

    // ---- Chunk: 8 groups at q0, outputs to regs ----
    f32x4 o0, o1, o2, o3, o4, o5, o6, o7;
#define OQ(oo, j)                                                         \
    do {                                                                  \
        int q = q0 + (j);                                                 \
        int A = q * 256 + (((l ^ q) & 63) << 1);                          \
        f32x2 xa = *(const f32x2*)&lx[A];                                 \
        f32x2 xb = *(const f32x2*)&lx[A + 128];                           \
        OSTEP_LO(xa, oo.x); OSTEP_HI(xa, oo.y);                           \
        OSTEP_LO(xb, oo.z); OSTEP_HI(xb, oo.w);                           \
    } while (0)
    OQ(o0, 0); OQ(o1, 1); OQ(o2, 2); OQ(o3, 3);
    OQ(o4, 4); OQ(o5, 5); OQ(o6, 6); OQ(o7, 7);

    // ---- Restage outputs into (consumed) chunk region of own LDS ----
#define OWR(oo, j)                                                        \
    do {                                                                  \
        int q = q0 + (j);                                                 \
        int A = q * 256 + (((l ^ q) & 63) << 1);                          \
        *(f32x2*)&lx[A]       = mk2((oo).x, (oo).y);                      \
        *(f32x2*)&lx[A + 128] = mk2((oo).z, (oo).w);                      \
    } while (0)
    OWR(o0, 0); OWR(o1, 1); OWR(o2, 2); OWR(o3, 3);
    OWR(o4, 4); OWR(o5, 5); OWR(o6, 6); OWR(o7, 7);

    // ---- Readback + coalesced nontemporal store ----
    float* og = out + (size_t)(sg * 64) * T_LEN + c * CHUNK;
    #pragma unroll
    for (int k = 0; k < 8; ++k) {
        int s = (l >> 3) + (k << 3);
        int j = l & 7;
        int q = q0 + j;
        int A = q * 256 + (((s ^ q) & 63) << 1);
        f32x2 lo = *(const f32x2*)&lx[A];
        f32x2 hi = *(const f32x2*)&lx[A + 128];
        f32x4 v; v.x = lo.x; v.y = lo.y; v.z = hi.x; v.w = hi.y;
        __builtin_nontemporal_store(v, (f32x4*)(og + (size_t)s * T_LEN + (j << 2)));
    }
}

extern "C" void kernel_launch(void* const* d_in, const int* in_sizes, int n_in,
                              void* d_out, int out_size, void* d_ws, size_t ws_size,
                              hipStream_t stream) {
    const float* x    = (const float*)d_in[0];
    const float* W_ih = (const float*)d_in[1];
    const float* W_hh = (const float*)d_in[2];
    const float* b_ih = (const float*)d_in[3];
    const float* b_hh = (const float*)d_in[4];
    const float* fc_w = (const float*)d_in[5];
    const float* fc_b = (const float*)d_in[6];
    float* out = (float*)d_out;

    const int B = in_sizes[0] / T_LEN;  // I == 1

    dim3 block(64);
    dim3 grid(B);                       // one wave per (64-seq group, chunk)
    rnn_wave<<<grid, block, 0, stream>>>(x, W_ih, W_hh, b_ih, b_hh,
                                         fc_w, fc_b, out);
}

// Round 8
// 20.489 us; speedup vs baseline: 1.2727x; 1.2727x over previous
//
#include <hip/hip_runtime.h>

// BSEC_RNN: B=4096, T=2048, I=1, H=2, O=1.
//   h[t] = tanh(W_ih*x[t] + b_ih + b_hh + W_hh @ h[t-1]),  h[-1] = 0
//   out[t] = fc_w[0]*x[t] + fc_w[1]*h0[t] + fc_w[2]*h1[t] + fc_b
//
// Parallel-in-time (validated r2-r7, absmax 3.9e-3 = fp32 baseline):
// chunks of 32 steps, 32-step warm-up from h=0.
//
// r8: r6 block structure (4 waves x [64 seqs, 4 chunks], pair-swizzled LDS,
// packed math) + 2 chunk-groups per block with T14 async-stage pipelining:
// group-B global loads are issued into regs BEFORE compute-A and stay in
// flight across it; ds_write-B lands post-barrier. Outputs restage into a
// SEPARATE 32KB LDS buffer (no x-buffer clobber barrier). 72KB LDS ->
// 2 blocks/CU; stage-B + store-A overlap compute.
//
// LDS x layout (validated r6): f4-group q = t/4 holds words
// [q*256 + 2*((seq^q)&63)] = (x_4q, x_4q+1), +128 = (x_4q+2, x_4q+3).
// Conflict-free staging writes and wave-uniform compute reads.
//
// Math (validated r6): state rr = (r0,r1), r = 1/(1+exp2(p)), h = 1-2r
// folded into coefficients; v_pk_fma_f32 op_sel broadcasts.
// Chain/step: pk_fma -> pk_fma -> v_exp -> pk_add -> v_rcp.

typedef float f32x2 __attribute__((ext_vector_type(2)));
typedef float f32x4 __attribute__((ext_vector_type(4)));

constexpr int T_LEN   = 2048;
constexpr int CHUNK   = 32;
constexpr int WARM    = 32;
constexpr int WPB     = 4;                 // waves (chunks) per block per group
constexpr int THREADS = 256;
constexpr int OSPAN   = WPB * CHUNK;       // 128 output floats/seq/group
constexpr int SPAN    = OSPAN + WARM;      // 160 staged x floats/seq
constexpr int NCG     = T_LEN / OSPAN;     // 16 chunk-groups
constexpr int XQ      = SPAN / 4;          // 40 x f4-groups

static __device__ inline float EXP2F(float x){ float r; asm("v_exp_f32 %0, %1":"=v"(r):"v"(x)); return r; }
static __device__ inline float RCPF(float x){ float r; asm("v_rcp_f32 %0, %1":"=v"(r):"v"(x)); return r; }
static __device__ inline f32x2 mk2(float a, float b){ f32x2 t; t.x=a; t.y=b; return t; }

#define PK_FMA_B0(d, s0, s1, s2)                                          \
    asm("v_pk_fma_f32 %0, %1, %2, %3 op_sel:[0,0,0] op_sel_hi:[0,1,1]"    \
        : "=v"(d) : "v"(s0), "v"(s1), "v"(s2))
#define PK_FMA_B1(d, s0, s1, s2)                                          \
    asm("v_pk_fma_f32 %0, %1, %2, %3 op_sel:[1,0,0] op_sel_hi:[1,1,1]"    \
        : "=v"(d) : "v"(s0), "v"(s1), "v"(s2))
#define PK_ADD(d, s0, s1)                                                 \
    asm("v_pk_add_f32 %0, %1, %2" : "=v"(d) : "v"(s0), "v"(s1))

#define PSTEP_CORE(bb)                                                    \
    do {                                                                  \
        f32x2 q_, p_, e_, d_;                                             \
        PK_FMA_B1(q_, rr, mm1, (bb));                                     \
        PK_FMA_B0(p_, rr, mm0, q_);                                       \
        e_.x = EXP2F(p_.x); e_.y = EXP2F(p_.y);                           \
        PK_ADD(d_, e_, ones);                                             \
        rr.x = RCPF(d_.x); rr.y = RCPF(d_.y);                             \
    } while (0)

#define WSTEP_LO(xp2) do { f32x2 b_; PK_FMA_B0(b_, (xp2), aa, cc); PSTEP_CORE(b_); } while (0)
#define WSTEP_HI(xp2) do { f32x2 b_; PK_FMA_B1(b_, (xp2), aa, cc); PSTEP_CORE(b_); } while (0)
#define OSTEP_LO(xp2, ok) do { WSTEP_LO(xp2); (ok) = fmaf(rr.y, g2, fmaf(rr.x, g1, fmaf((xp2).x, f0, fb))); } while (0)
#define OSTEP_HI(xp2, ok) do { WSTEP_HI(xp2); (ok) = fmaf(rr.y, g2, fmaf(rr.x, g1, fmaf((xp2).y, f0, fb))); } while (0)

// Issue 10 coalesced f32x4 global loads into regs (fully unrolled -> static).
#define LOADX(dst, xgp)                                                   \
    do {                                                                  \
        _Pragma("unroll")                                                 \
        for (int k = 0; k < 10; ++k) {                                    \
            int idx = k * THREADS + tid;                                  \
            int r_ = idx / XQ, c_ = idx - r_ * XQ;                        \
            dst[k] = *(const f32x4*)((xgp) + (size_t)r_ * T_LEN + c_ * 4);\
        }                                                                 \
    } while (0)

// ds_write the staged regs into pair-swizzled x LDS.
#define WRITEX(src)                                                       \
    do {                                                                  \
        _Pragma("unroll")                                                 \
        for (int k = 0; k < 10; ++k) {                                    \
            int idx = k * THREADS + tid;                                  \
            int r_ = idx / XQ, c_ = idx - r_ * XQ;                        \
            int A_ = c_ * 256 + (((r_ ^ c_) & 63) << 1);                  \
            *(f32x2*)&lx[A_]       = mk2(src[k].x, src[k].y);             \
            *(f32x2*)&lx[A_ + 128] = mk2(src[k].z, src[k].w);             \
        }                                                                 \
    } while (0)

// Compute one chunk-group cg from lx; outputs -> lo_buf (own-wave region).
#define COMPUTE_OWR(cg)                                                   \
    do {                                                                  \
        int q, warm_q;                                                    \
        if ((cg) == 0) {                                                  \
            int gt = w * CHUNK - WARM; if (gt < 0) gt = 0;                \
            q = gt >> 2; warm_q = (w * CHUNK - gt) >> 2;                  \
        } else {                                                          \
            q = (w * CHUNK) >> 2; warm_q = WARM >> 2;                     \
        }                                                                 \
        f32x2 rr = mk2(0.5f, 0.5f);                                       \
        _Pragma("unroll 2")                                               \
        for (int i = 0; i < warm_q; ++i, ++q) {                           \
            int A_ = q * 256 + (((l ^ q) & 63) << 1);                     \
            f32x2 xa_ = *(const f32x2*)&lx[A_];                           \
            f32x2 xb_ = *(const f32x2*)&lx[A_ + 128];                     \
            WSTEP_LO(xa_); WSTEP_HI(xa_); WSTEP_LO(xb_); WSTEP_HI(xb_);   \
        }                                                                 \
        _Pragma("unroll")                                                 \
        for (int j = 0; j < 8; ++j, ++q) {                                \
            int A_ = q * 256 + (((l ^ q) & 63) << 1);                     \
            f32x2 xa_ = *(const f32x2*)&lx[A_];                           \
            f32x2 xb_ = *(const f32x2*)&lx[A_ + 128];                     \
            f32x4 oo;                                                     \
            OSTEP_LO(xa_, oo.x); OSTEP_HI(xa_, oo.y);                     \
            OSTEP_LO(xb_, oo.z); OSTEP_HI(xb_, oo.w);                     \
            int qo = w * 8 + j;                                           \
            int Ao = qo * 256 + (((l ^ qo) & 63) << 1);                   \
            *(f32x2*)&lo_buf[Ao]       = mk2(oo.x, oo.y);                 \
            *(f32x2*)&lo_buf[Ao + 128] = mk2(oo.z, oo.w);                 \
        }                                                                 \
    } while (0)

// Cross-wave readback of lo_buf + coalesced NT store of chunk-group cg.
#define STOREO(cg)                                                        \
    do {                                                                  \
        float* og = out + (size_t)(sg * 64) * T_LEN + (cg) * OSPAN;       \
        _Pragma("unroll")                                                 \
        for (int k = 0; k < 8; ++k) {                                     \
            int idx = k * THREADS + tid;                                  \
            int r_ = idx >> 5, c_ = idx & 31;                             \
            int A_ = c_ * 256 + (((r_ ^ c_) & 63) << 1);                  \
            f32x2 lo_ = *(const f32x2*)&lo_buf[A_];                       \
            f32x2 hi_ = *(const f32x2*)&lo_buf[A_ + 128];                 \
            f32x4 v_; v_.x = lo_.x; v_.y = lo_.y; v_.z = hi_.x; v_.w = hi_.y; \
            __builtin_nontemporal_store(v_,                               \
                (f32x4*)(og + (size_t)r_ * T_LEN + c_ * 4));              \
        }                                                                 \
    } while (0)

__global__ __launch_bounds__(THREADS, 2) void rnn_pipe(
    const float* __restrict__ x,
    const float* __restrict__ W_ih,
    const float* __restrict__ W_hh,
    const float* __restrict__ b_ih,
    const float* __restrict__ b_hh,
    const float* __restrict__ fc_w,
    const float* __restrict__ fc_b,
    float* __restrict__ out)
{
    __shared__ float lx[SPAN * 64];       // 40 KB x staging
    __shared__ float lo_buf[OSPAN * 64];  // 32 KB output staging

    const int sg  = blockIdx.x >> 3;      // sequence group (64 seqs)
    const int bcg = blockIdx.x & 7;       // chunk-group pair index
    const int cgA = bcg * 2, cgB = bcg * 2 + 1;
    const int tid = threadIdx.x;
    const int w = tid >> 6, l = tid & 63;

    const float* xbase = x + (size_t)(sg * 64) * T_LEN;
    const int tloA = cgA ? cgA * OSPAN - WARM : 0;
    const int tloB = cgB * OSPAN - WARM;  // cgB >= 1 always

    // ---- Coefficients (r-trick folding, s = 2*log2(e)) ----
    const float s2 = 2.0f * 1.44269504088896340736f;
    const float W00 = W_hh[0], W01 = W_hh[1], W10 = W_hh[2], W11 = W_hh[3];
    const f32x2 aa  = mk2(W_ih[0] * s2, W_ih[1] * s2);
    const f32x2 cc  = mk2((b_ih[0] + b_hh[0] + W00 + W01) * s2,
                          (b_ih[1] + b_hh[1] + W10 + W11) * s2);
    const f32x2 mm0 = mk2(-2.0f * s2 * W00, -2.0f * s2 * W10);
    const f32x2 mm1 = mk2(-2.0f * s2 * W01, -2.0f * s2 * W11);
    const f32x2 ones = mk2(1.0f, 1.0f);
    const float f0 = fc_w[0];
    const float g1 = -2.0f * fc_w[1], g2 = -2.0f * fc_w[2];
    const float fb = fc_b[0] + fc_w[1] + fc_w[2];

    f32x4 rbuf[10];

    // ---- Prologue: stage A ----
    LOADX(rbuf, xbase + tloA);
    WRITEX(rbuf);
    __syncthreads();                       // (1) x-A visible

    // ---- Iter A: prefetch B during compute ----
    LOADX(rbuf, xbase + tloB);             // in flight across compute-A
    COMPUTE_OWR(cgA);
    __syncthreads();                       // (2) x-A reads done; lo_buf-A visible
    WRITEX(rbuf);                          // ds_write B (vmcnt-ordered)
    STOREO(cgA);                           // overlap with B staging
    __syncthreads();                       // (3) x-B visible; lo_buf-A reads done

    // ---- Iter B ----
    COMPUTE_OWR(cgB);
    __syncthreads();                       // (4) lo_buf-B visible
    STOREO(cgB);
}

extern "C" void kernel_launch(void* const* d_in, const int* in_sizes, int n_in,
                              void* d_out, int out_size, void* d_ws, size_t ws_size,
                              hipStream_t stream) {
    const float* x    = (const float*)d_in[0];
    const float* W_ih = (const float*)d_in[1];
    const float* W_hh = (const float*)d_in[2];
    const float* b_ih = (const float*)d_in[3];
    const float* b_hh = (const float*)d_in[4];
    const float* fc_w = (const float*)d_in[5];
    const float* fc_b = (const float*)d_in[6];
    float* out = (float*)d_out;

    const int B = in_sizes[0] / T_LEN;  // I == 1

    dim3 block(THREADS);
    dim3 grid((B / 64) * (NCG / 2));    // 512 blocks = 2/CU
    rnn_pipe<<<grid, block, 0, stream>>>(x, W_ih, W_hh, b_ih, b_hh,
                                         fc_w, fc_b, out);
}